// Round 12
// baseline (32.751 us; speedup 1.0000x reference)
//
#include <hip/hip_runtime.h>
#include <math.h>

// PhaseLoss: ip + gd + ptd phase losses over [32,1,513,512] fp32 spectra.
// d'[b,f,t] = angle(ref * conj(est)); ip = |d'|;
// gd  = unwrap(d'[f-1,t] - d'[f,t])  (f-1<0 -> 0)
// ptd = unwrap(d'[f,t-1] - d'[f,t])  (t-1<0 -> 0)
// out = sum / (B*F*T)
//
// R12 = R10 structure + NONTEMPORAL loads (R11 retry; the builtin needs a
// clang ext_vector pointer, not HIP_vector_type float4*). Pure cache-policy
// A/B vs R10: we stream 134 MB once through 32 MB of L2; nt = evict-first
// hint removes fill/evict thrash if that's what caps delivered BW at
// ~4.3 TB/s. Everything else identical to R10:
// exact-fit persistent grid, 512 blocks = 2/CU, rows flattened to 16416x512,
// blocks 0..479 own 32 rows / 480..511 own 33, in-block halo sharing via
// seed phase (+1 barrier), batch boundary = gd-carry reset at f==0.
// R4/R6 lessons: no fences, no hot atomics; plain slot store + finalize.

#define NB 32
#define NF 513
#define NT 512
#define NROWS 16416        // 32*513
#define NBLOCKS 512
#define NTOT 8404992LL     // 32*513*512

typedef float f32x4 __attribute__((ext_vector_type(4)));

static __device__ __forceinline__ float fast_atan2(float y, float x) {
    const float PI_F  = 3.14159274101257324f;
    const float PI_2F = 1.57079632679489662f;
    float ax = fabsf(x), ay = fabsf(y);
    float mx = fmaxf(ax, ay), mn = fminf(ax, ay);
    float r  = mn * __builtin_amdgcn_rcpf(mx);
    r = (mx == 0.f) ? 0.f : r;
    float s = r * r;
    float p = fmaf(s, -0.01172120f, 0.05265332f);
    p = fmaf(s, p, -0.11643287f);
    p = fmaf(s, p,  0.19354346f);
    p = fmaf(s, p, -0.33262347f);
    p = fmaf(s, p,  0.99997726f);
    float a = r * p;
    a = (ay > ax) ? (PI_2F - a) : a;
    a = (x < 0.f) ? (PI_F - a) : a;
    return copysignf(a, y);
}

static __device__ __forceinline__ float pdiff(float a, float b, float c, float d) {
    // est=a+ib, ref=c+id: angle(ref*conj(est)) = atan2(d*a - c*b, c*a + d*b)
    return fast_atan2(fmaf(d, a, -(c * b)), fmaf(c, a, d * b));
}

static __device__ __forceinline__ float wrap_abs(float x) {
    const float PI_F     = 3.14159274101257324f;
    const float TWO_PI_F = 6.28318548202514648f;
    float u = fabsf(x);
    return u > PI_F ? TWO_PI_F - u : u;
}

struct Row8 { f32x4 a0, a1, b0, b1, c0, c1, e0, e1; };

static __device__ __forceinline__ void calc8(const Row8& r, float d[8]) {
    d[0] = pdiff(r.a0.x, r.b0.x, r.c0.x, r.e0.x);
    d[1] = pdiff(r.a0.y, r.b0.y, r.c0.y, r.e0.y);
    d[2] = pdiff(r.a0.z, r.b0.z, r.c0.z, r.e0.z);
    d[3] = pdiff(r.a0.w, r.b0.w, r.c0.w, r.e0.w);
    d[4] = pdiff(r.a1.x, r.b1.x, r.c1.x, r.e1.x);
    d[5] = pdiff(r.a1.y, r.b1.y, r.c1.y, r.e1.y);
    d[6] = pdiff(r.a1.z, r.b1.z, r.c1.z, r.e1.z);
    d[7] = pdiff(r.a1.w, r.b1.w, r.c1.w, r.e1.w);
}

// accumulate one row's three loss terms; updates dp[] (f-1 carry)
static __device__ __forceinline__ float acc_row(const float d[8], float dp[8], int lane) {
    float dt = __shfl_up(d[7], 1, 64);
    if (lane == 0) dt = 0.f;                  // t==0 neighbor
    float s = 0.f;
    #pragma unroll
    for (int k = 0; k < 8; ++k) {
        s += fabsf(d[k]);                     // ip
        s += wrap_abs(dp[k] - d[k]);          // gd
        s += wrap_abs(dt - d[k]);             // ptd
        dt = d[k];
        dp[k] = d[k];
    }
    return s;
}

__global__ __launch_bounds__(256) void phase_loss_k(
    const float* __restrict__ er, const float* __restrict__ ei,
    const float* __restrict__ rr, const float* __restrict__ ri,
    float* __restrict__ slots)
{
    __shared__ float halo[4][NT];             // d of row preceding wave w's span
    __shared__ float ws4[4];
    const int tid  = threadIdx.x;
    const int lane = tid & 63;
    const int wave = tid >> 6;
    const int bid  = blockIdx.x;

    // block row-span: exact cover of 16416 rows by 512 blocks (32 or 33 rows)
    int R0, N;
    if (bid < 480) { R0 = bid * 32;                  N = 32; }
    else           { R0 = 15360 + (bid - 480) * 33;  N = 33; }
    const int r0w = R0 + wave * 8;                   // wave's first row
    const int nw  = (wave == 3) ? (N - 24) : 8;      // 8, or 9 for wave3 of 33-row blocks
    const int fw  = r0w % NF;                        // f of first row

#define NTL(p) __builtin_nontemporal_load((const f32x4*)(p))
#define LOAD_ROWR(dst, row_) do {                                \
        const int _i = (row_) * NT + lane * 8;                   \
        dst.a0 = NTL(er + _i);                                   \
        dst.a1 = NTL(er + _i + 4);                               \
        dst.b0 = NTL(ei + _i);                                   \
        dst.b1 = NTL(ei + _i + 4);                               \
        dst.c0 = NTL(rr + _i);                                   \
        dst.c1 = NTL(rr + _i + 4);                               \
        dst.e0 = NTL(ri + _i);                                   \
        dst.e1 = NTL(ri + _i + 4);                               \
    } while (0)

    // ---- seed phase: waves 0..2 compute d of their LAST row -> halo[w+1];
    //      wave 0 loads the block-halo row (R0-1) unless f==0 there ----
    Row8 R7, Rh;
    float d7[8];
    const bool haveSeed = (wave < 3);
    const bool whalo    = (wave == 0) && (fw != 0);
    if (haveSeed) LOAD_ROWR(R7, r0w + 7);
    if (whalo)    LOAD_ROWR(Rh, r0w - 1);
    if (haveSeed) {
        calc8(R7, d7);
        *(float4*)&halo[wave + 1][lane * 8]     = make_float4(d7[0], d7[1], d7[2], d7[3]);
        *(float4*)&halo[wave + 1][lane * 8 + 4] = make_float4(d7[4], d7[5], d7[6], d7[7]);
    }
    if (whalo) {
        float dh[8];
        calc8(Rh, dh);
        *(float4*)&halo[0][lane * 8]     = make_float4(dh[0], dh[1], dh[2], dh[3]);
        *(float4*)&halo[0][lane * 8 + 4] = make_float4(dh[4], dh[5], dh[6], dh[7]);
    }
    __syncthreads();

    // ---- main loop: fresh rows (7 for seed-waves, nw for wave 3);
    //      seed-waves append their register-carried row 7 ----
    float dp[8];
    if (fw != 0) {
        float4 h0 = *(const float4*)&halo[wave][lane * 8];
        float4 h1 = *(const float4*)&halo[wave][lane * 8 + 4];
        dp[0] = h0.x; dp[1] = h0.y; dp[2] = h0.z; dp[3] = h0.w;
        dp[4] = h1.x; dp[5] = h1.y; dp[6] = h1.z; dp[7] = h1.w;
    } else {
        #pragma unroll
        for (int k = 0; k < 8; ++k) dp[k] = 0.f;
    }

    float s = 0.f;
    const int nfresh = haveSeed ? 7 : nw;
    int f = fw;
    Row8 cur, nxt;
    LOAD_ROWR(nxt, r0w);
    for (int i = 0; i < nfresh; ++i) {
        cur = nxt;
        if (i + 1 < nfresh) LOAD_ROWR(nxt, r0w + i + 1);
        float d[8];
        calc8(cur, d);
        if (f == 0) {                          // batch boundary: reset gd carry
            #pragma unroll
            for (int k = 0; k < 8; ++k) dp[k] = 0.f;
        }
        s += acc_row(d, dp, lane);
        if (++f == NF) f = 0;
    }
    if (haveSeed) {                            // row r0w+7, d already in regs
        if (f == 0) {
            #pragma unroll
            for (int k = 0; k < 8; ++k) dp[k] = 0.f;
        }
        s += acc_row(d7, dp, lane);
    }
#undef LOAD_ROWR
#undef NTL

    // per-wave reduce, tiny cross-wave combine, one plain store per block
    #pragma unroll
    for (int off = 32; off > 0; off >>= 1)
        s += __shfl_down(s, off, 64);
    if (lane == 0) ws4[wave] = s;
    __syncthreads();
    if (tid == 0) slots[bid] = ws4[0] + ws4[1] + ws4[2] + ws4[3];
}

__global__ __launch_bounds__(256) void finalize_k(const float* __restrict__ slots,
                                                  float* __restrict__ out)
{
    int tid = threadIdx.x;
    float s = 0.f;
    for (int i = tid; i < NBLOCKS; i += 256) s += slots[i];
    #pragma unroll
    for (int off = 32; off > 0; off >>= 1)
        s += __shfl_down(s, off, 64);
    __shared__ float wsum[4];
    if ((tid & 63) == 0) wsum[tid >> 6] = s;
    __syncthreads();
    if (tid == 0) {
        double tot = (double)wsum[0] + (double)wsum[1] + (double)wsum[2] + (double)wsum[3];
        out[0] = (float)(tot / (double)NTOT);
    }
}

extern "C" void kernel_launch(void* const* d_in, const int* in_sizes, int n_in,
                              void* d_out, int out_size, void* d_ws, size_t ws_size,
                              hipStream_t stream) {
    const float* er = (const float*)d_in[0];
    const float* ei = (const float*)d_in[1];
    const float* rr = (const float*)d_in[2];
    const float* ri = (const float*)d_in[3];
    float* out   = (float*)d_out;
    float* slots = (float*)d_ws;              // NBLOCKS fp32, fully rewritten each call

    phase_loss_k<<<NBLOCKS, 256, 0, stream>>>(er, ei, rr, ri, slots);
    finalize_k<<<1, 256, 0, stream>>>(slots, out);
}